// Round 2
// baseline (1367.280 us; speedup 1.0000x reference)
//
#include <hip/hip_runtime.h>
#include <cstdint>
#include <cstddef>

#define DIV_UP(a, b) (((a) + (b) - 1) / (b))

// ---------------- bf16 helpers (RNE) ----------------

__device__ __forceinline__ float b2f(unsigned short u) {
  unsigned int x = ((unsigned int)u) << 16;
  float f;
  __builtin_memcpy(&f, &x, 4);
  return f;
}
__device__ __forceinline__ unsigned short f2b(float f) {
  unsigned int x;
  __builtin_memcpy(&x, &f, 4);
  unsigned int r = (x + 0x7FFFu + ((x >> 16) & 1u)) >> 16;
  return (unsigned short)r;
}

__device__ __forceinline__ float ld1(const float* p) { return *p; }
__device__ __forceinline__ float ld1(const unsigned short* p) { return b2f(*p); }
__device__ __forceinline__ void st1(float* p, float v) { *p = v; }
__device__ __forceinline__ void st1(unsigned short* p, float v) { *p = f2b(v); }

__device__ __forceinline__ float2 ld2(const float* p) { return *reinterpret_cast<const float2*>(p); }
__device__ __forceinline__ float2 ld2(const unsigned short* p) {
  ushort2 u = *reinterpret_cast<const ushort2*>(p);
  return make_float2(b2f(u.x), b2f(u.y));
}
__device__ __forceinline__ void st2(float* p, float2 v) { *reinterpret_cast<float2*>(p) = v; }
__device__ __forceinline__ void st2(unsigned short* p, float2 v) {
  ushort2 u;
  u.x = f2b(v.x);
  u.y = f2b(v.y);
  *reinterpret_cast<ushort2*>(p) = u;
}

__device__ __forceinline__ float4 ld4(const float* p) { return *reinterpret_cast<const float4*>(p); }
__device__ __forceinline__ float4 ld4(const unsigned short* p) {
  ushort4 u = *reinterpret_cast<const ushort4*>(p);
  return make_float4(b2f(u.x), b2f(u.y), b2f(u.z), b2f(u.w));
}
__device__ __forceinline__ void st4(float* p, float4 v) { *reinterpret_cast<float4*>(p) = v; }
__device__ __forceinline__ void st4(unsigned short* p, float4 v) {
  ushort4 u;
  u.x = f2b(v.x);
  u.y = f2b(v.y);
  u.z = f2b(v.z);
  u.w = f2b(v.w);
  *reinterpret_cast<ushort4*>(p) = u;
}

// ---------------- CSR build ----------------

__global__ void count_kernel(const int* __restrict__ dst, int* __restrict__ cnt, int E) {
  int e = blockIdx.x * blockDim.x + threadIdx.x;
  if (e < E) atomicAdd(&cnt[dst[e]], 1);
}

// chunk = 1024 elements per block (256 threads x 4)
__global__ void scan1_kernel(const int* __restrict__ cnt, int* __restrict__ rowstart,
                             int* __restrict__ bsums, int n) {
  __shared__ int sh[256];
  const int tid = threadIdx.x;
  const int base = blockIdx.x * 1024 + tid * 4;
  int c0 = (base + 0 < n) ? cnt[base + 0] : 0;
  int c1 = (base + 1 < n) ? cnt[base + 1] : 0;
  int c2 = (base + 2 < n) ? cnt[base + 2] : 0;
  int c3 = (base + 3 < n) ? cnt[base + 3] : 0;
  sh[tid] = c0 + c1 + c2 + c3;
  __syncthreads();
  for (int off = 1; off < 256; off <<= 1) {
    int v = (tid >= off) ? sh[tid - off] : 0;
    __syncthreads();
    sh[tid] += v;
    __syncthreads();
  }
  int excl = (tid > 0) ? sh[tid - 1] : 0;
  if (base + 0 < n) rowstart[base + 0] = excl;
  if (base + 1 < n) rowstart[base + 1] = excl + c0;
  if (base + 2 < n) rowstart[base + 2] = excl + c0 + c1;
  if (base + 3 < n) rowstart[base + 3] = excl + c0 + c1 + c2;
  if (tid == 255) bsums[blockIdx.x] = sh[255];
}

__global__ void scan2_kernel(int* __restrict__ bsums, int nb) {
  __shared__ int sh[512];
  const int tid = threadIdx.x;
  int v = (tid < nb) ? bsums[tid] : 0;
  sh[tid] = v;
  __syncthreads();
  for (int off = 1; off < 512; off <<= 1) {
    int t = (tid >= off) ? sh[tid - off] : 0;
    __syncthreads();
    sh[tid] += t;
    __syncthreads();
  }
  int excl = (tid > 0) ? sh[tid - 1] : 0;
  if (tid < nb) bsums[tid] = excl;
}

__global__ void scan3_kernel(int* __restrict__ rowstart, const int* __restrict__ bsums,
                             int* __restrict__ cursor, const int* __restrict__ cnt,
                             float* __restrict__ dinv, int n, int E) {
  int i = blockIdx.x * blockDim.x + threadIdx.x;
  if (i < n) {
    int rs = rowstart[i] + bsums[i >> 10];
    rowstart[i] = rs;
    cursor[i] = rs;
    dinv[i] = rsqrtf((float)cnt[i] + 1.0f);  // +1 for self-loop
  }
  if (i == 0) rowstart[n] = E;
}

__global__ void fill_kernel(const int* __restrict__ src, const int* __restrict__ dst,
                            const float* __restrict__ dinv, int* __restrict__ cursor,
                            int* __restrict__ col, float* __restrict__ ew, int E) {
  int e = blockIdx.x * blockDim.x + threadIdx.x;
  if (e < E) {
    int s = src[e], d = dst[e];
    int pos = atomicAdd(&cursor[d], 1);
    col[pos] = s;
    ew[pos] = dinv[s] * dinv[d];
  }
}

// ---------------- aggregation: one wave (64 lanes) per node ----------------

template <int F, typename TIN, typename TOUT>  // F = 64 or 128 features
__global__ __launch_bounds__(256) void agg_kernel(const TIN* __restrict__ v,
                                                  const float* __restrict__ dinv,
                                                  const int* __restrict__ rowstart,
                                                  const int* __restrict__ col,
                                                  const float* __restrict__ ew,
                                                  TOUT* __restrict__ out, int n) {
  int w = (blockIdx.x * blockDim.x + threadIdx.x) >> 6;
  int lane = threadIdx.x & 63;
  if (w >= n) return;
  float di = dinv[w];
  float sw = di * di;  // self-loop weight
  int r0 = rowstart[w], r1 = rowstart[w + 1];
  if (F == 64) {
    float acc = sw * ld1(v + (size_t)w * 64 + lane);
    for (int k = r0; k < r1; ++k) {
      acc += ew[k] * ld1(v + (size_t)col[k] * 64 + lane);
    }
    st1(out + (size_t)w * 64 + lane, acc);
  } else {
    float2 a = ld2(v + (size_t)w * 128 + 2 * lane);
    float2 acc;
    acc.x = sw * a.x;
    acc.y = sw * a.y;
    for (int k = r0; k < r1; ++k) {
      float wgt = ew[k];
      float2 b = ld2(v + (size_t)col[k] * 128 + 2 * lane);
      acc.x += wgt * b.x;
      acc.y += wgt * b.y;
    }
    st2(out + (size_t)w * 128 + 2 * lane, acc);
  }
}

// layer-3 aggregation fused with bias + relu + mean-pool accumulation (F = 64)
template <typename TIN>
__global__ __launch_bounds__(256) void agg_pool_kernel(
    const TIN* __restrict__ v, const float* __restrict__ dinv,
    const int* __restrict__ rowstart, const int* __restrict__ col,
    const float* __restrict__ ew, const float* __restrict__ b3,
    const int* __restrict__ batch, float* __restrict__ psum,
    float* __restrict__ pcnt, int n) {
  int w = (blockIdx.x * blockDim.x + threadIdx.x) >> 6;
  int lane = threadIdx.x & 63;
  if (w >= n) return;
  float di = dinv[w];
  float acc = di * di * ld1(v + (size_t)w * 64 + lane);
  int r0 = rowstart[w], r1 = rowstart[w + 1];
  for (int k = r0; k < r1; ++k) {
    acc += ew[k] * ld1(v + (size_t)col[k] * 64 + lane);
  }
  float h = fmaxf(acc + b3[lane], 0.0f);
  int g = batch[w];
  atomicAdd(&psum[(size_t)g * 64 + lane], h);
  if (lane == 0) atomicAdd(&pcnt[g], 1.0f);
}

// ---------------- GEMM: [n,K] @ [K,NC] + bias (+relu), fp32 accumulate ----------------
// W + bias staged in LDS once per block; grid-stride over 32-row tiles.

template <int K, int NC, bool RELU, typename TIN, typename TOUT>
__global__ __launch_bounds__(256, 2) void gemm_kernel(const TIN* __restrict__ A,
                                                      const float* __restrict__ W,
                                                      const float* __restrict__ bias,
                                                      TOUT* __restrict__ out, int n) {
  constexpr int CG = NC / 4;    // col groups (float4)
  constexpr int RQN = 256 / CG; // row groups per block
  constexpr int RPT = 32 / RQN; // rows per thread
  __shared__ float Wl[K * NC];
  __shared__ float bl[NC];
  for (int idx = threadIdx.x; idx < (K * NC) / 4; idx += 256)
    reinterpret_cast<float4*>(Wl)[idx] = reinterpret_cast<const float4*>(W)[idx];
  if (threadIdx.x < NC) bl[threadIdx.x] = bias ? bias[threadIdx.x] : 0.0f;
  __syncthreads();
  const int cg = threadIdx.x % CG;
  const int rq = threadIdx.x / CG;
  const int ntiles = DIV_UP(n, 32);
  const float4* Wl4 = reinterpret_cast<const float4*>(Wl);
  for (int tile = blockIdx.x; tile < ntiles; tile += (int)gridDim.x) {
    const int row0 = tile * 32 + rq * RPT;
    float acc[RPT][4] = {};
    if (row0 + RPT <= n) {
#pragma unroll 4
      for (int k = 0; k < K; k += 4) {
        float4 w0 = Wl4[(k + 0) * CG + cg];
        float4 w1 = Wl4[(k + 1) * CG + cg];
        float4 w2 = Wl4[(k + 2) * CG + cg];
        float4 w3 = Wl4[(k + 3) * CG + cg];
#pragma unroll
        for (int r = 0; r < RPT; ++r) {
          float4 a = ld4(A + (size_t)(row0 + r) * K + k);
          acc[r][0] += a.x * w0.x; acc[r][1] += a.x * w0.y; acc[r][2] += a.x * w0.z; acc[r][3] += a.x * w0.w;
          acc[r][0] += a.y * w1.x; acc[r][1] += a.y * w1.y; acc[r][2] += a.y * w1.z; acc[r][3] += a.y * w1.w;
          acc[r][0] += a.z * w2.x; acc[r][1] += a.z * w2.y; acc[r][2] += a.z * w2.z; acc[r][3] += a.z * w2.w;
          acc[r][0] += a.w * w3.x; acc[r][1] += a.w * w3.y; acc[r][2] += a.w * w3.z; acc[r][3] += a.w * w3.w;
        }
      }
      const float bx = bl[cg * 4 + 0], by = bl[cg * 4 + 1];
      const float bz = bl[cg * 4 + 2], bw = bl[cg * 4 + 3];
#pragma unroll
      for (int r = 0; r < RPT; ++r) {
        float o0 = acc[r][0] + bx, o1 = acc[r][1] + by;
        float o2 = acc[r][2] + bz, o3 = acc[r][3] + bw;
        if (RELU) {
          o0 = fmaxf(o0, 0.f); o1 = fmaxf(o1, 0.f);
          o2 = fmaxf(o2, 0.f); o3 = fmaxf(o3, 0.f);
        }
        float4 ov; ov.x = o0; ov.y = o1; ov.z = o2; ov.w = o3;
        st4(out + (size_t)(row0 + r) * NC + cg * 4, ov);
      }
    } else {
      for (int k = 0; k < K; k += 4) {
        float4 w0 = Wl4[(k + 0) * CG + cg];
        float4 w1 = Wl4[(k + 1) * CG + cg];
        float4 w2 = Wl4[(k + 2) * CG + cg];
        float4 w3 = Wl4[(k + 3) * CG + cg];
        for (int r = 0; r < RPT; ++r) {
          int row = row0 + r;
          if (row < n) {
            float4 a = ld4(A + (size_t)row * K + k);
            acc[r][0] += a.x * w0.x; acc[r][1] += a.x * w0.y; acc[r][2] += a.x * w0.z; acc[r][3] += a.x * w0.w;
            acc[r][0] += a.y * w1.x; acc[r][1] += a.y * w1.y; acc[r][2] += a.y * w1.z; acc[r][3] += a.y * w1.w;
            acc[r][0] += a.z * w2.x; acc[r][1] += a.z * w2.y; acc[r][2] += a.z * w2.z; acc[r][3] += a.z * w2.w;
            acc[r][0] += a.w * w3.x; acc[r][1] += a.w * w3.y; acc[r][2] += a.w * w3.z; acc[r][3] += a.w * w3.w;
          }
        }
      }
      for (int r = 0; r < RPT; ++r) {
        int row = row0 + r;
        if (row < n) {
          float o0 = acc[r][0] + bl[cg * 4 + 0], o1 = acc[r][1] + bl[cg * 4 + 1];
          float o2 = acc[r][2] + bl[cg * 4 + 2], o3 = acc[r][3] + bl[cg * 4 + 3];
          if (RELU) {
            o0 = fmaxf(o0, 0.f); o1 = fmaxf(o1, 0.f);
            o2 = fmaxf(o2, 0.f); o3 = fmaxf(o3, 0.f);
          }
          float4 ov; ov.x = o0; ov.y = o1; ov.z = o2; ov.w = o3;
          st4(out + (size_t)row * NC + cg * 4, ov);
        }
      }
    }
  }
}

// ---------------- 5-task MLP heads: one thread per (t, g) output ----------------

__global__ __launch_bounds__(256) void heads_kernel(const float* __restrict__ psum,
                                                    const float* __restrict__ pcnt,
                                                    const float* __restrict__ Wa,
                                                    const float* __restrict__ ba,
                                                    const float* __restrict__ Wb,
                                                    const float* __restrict__ bb,
                                                    float* __restrict__ outp, int G) {
  int gid = blockIdx.x * blockDim.x + threadIdx.x;
  if (gid >= 5 * G) return;
  int g = gid % G;  // consecutive lanes -> consecutive g, uniform t per wave
  int t = gid / G;
  float inv = 1.0f / fmaxf(pcnt[g], 1.0f);
  const float* Wat = Wa + (size_t)t * 64 * 32;
  float hid[32];
#pragma unroll
  for (int j = 0; j < 32; ++j) hid[j] = ba[t * 32 + j];
  for (int d = 0; d < 64; ++d) {
    float pd = psum[(size_t)g * 64 + d] * inv;
#pragma unroll
    for (int j = 0; j < 32; ++j) hid[j] += pd * Wat[d * 32 + j];
  }
  float o = bb[t];
#pragma unroll
  for (int j = 0; j < 32; ++j) o += fmaxf(hid[j], 0.0f) * Wb[t * 32 + j];
  outp[(size_t)t * G + g] = o;
}

// ---------------- pipeline over activations of storage type ST ----------------

template <typename ST>
static void run_pipeline(const float* x, const float* W1, const float* b1,
                         const float* W2, const float* b2, const float* W3,
                         const float* b3, const int* batch, const float* dinv,
                         const int* rowstart, const int* colw, const float* ew,
                         ST* bufA, ST* bufB, float* psum, float* pcnt, int N,
                         hipStream_t stream) {
  // t1 [N,64] in bufB; h1 [N,128] in bufA; t2 [N,128] in bufB (t1 dead);
  // h2 [N,128] in bufA (h1 dead); hw3 [N,64] in bufB (t2 dead).
  agg_kernel<64, float, ST><<<DIV_UP(N, 4), 256, 0, stream>>>(x, dinv, rowstart, colw, ew, bufB, N);
  gemm_kernel<64, 128, true, ST, ST><<<2048, 256, 0, stream>>>(bufB, W1, b1, bufA, N);
  agg_kernel<128, ST, ST><<<DIV_UP(N, 4), 256, 0, stream>>>(bufA, dinv, rowstart, colw, ew, bufB, N);
  gemm_kernel<128, 128, true, ST, ST><<<2048, 256, 0, stream>>>(bufB, W2, b2, bufA, N);
  gemm_kernel<128, 64, false, ST, ST><<<2048, 256, 0, stream>>>(bufA, W3, nullptr, bufB, N);
  agg_pool_kernel<ST><<<DIV_UP(N, 4), 256, 0, stream>>>(bufB, dinv, rowstart, colw, ew, b3, batch, psum, pcnt, N);
}

// ---------------- launch ----------------

extern "C" void kernel_launch(void* const* d_in, const int* in_sizes, int n_in,
                              void* d_out, int out_size, void* d_ws, size_t ws_size,
                              hipStream_t stream) {
  (void)n_in;
  const float* x  = (const float*)d_in[0];
  const int* ei   = (const int*)d_in[1];
  const int* batch = (const int*)d_in[2];
  const float* W1 = (const float*)d_in[3];
  const float* b1 = (const float*)d_in[4];
  const float* W2 = (const float*)d_in[5];
  const float* b2 = (const float*)d_in[6];
  const float* W3 = (const float*)d_in[7];
  const float* b3 = (const float*)d_in[8];
  const float* Wa = (const float*)d_in[9];
  const float* ba = (const float*)d_in[10];
  const float* Wb = (const float*)d_in[11];
  const float* bb = (const float*)d_in[12];
  float* out = (float*)d_out;

  const int N = in_sizes[0] / 64;
  const int E = in_sizes[1] / 2;
  const int G = out_size / 5;
  const int* src = ei;
  const int* dst = ei + E;

  char* ws = (char*)d_ws;
  size_t off = 0;
  auto alloc = [&](size_t bytes) -> char* {
    char* p = ws + off;
    off = (off + bytes + 255) & ~(size_t)255;
    return p;
  };
  int* cnt      = (int*)alloc((size_t)N * 4);
  int* rowstart = (int*)alloc((size_t)(N + 1) * 4);
  int* cursor   = (int*)alloc((size_t)N * 4);
  int* colw     = (int*)alloc((size_t)E * 4);
  float* ew     = (float*)alloc((size_t)E * 4);
  float* dinv   = (float*)alloc((size_t)N * 4);
  const int nchunks = DIV_UP(N, 1024);  // 391 for N=400000 (<= 512)
  int* bsums    = (int*)alloc((size_t)nchunks * 4);
  float* psum   = (float*)alloc((size_t)G * 64 * 4);
  float* pcnt   = (float*)alloc((size_t)G * 4);

  const size_t act_elems = (size_t)N * 128;
  const size_t need_f32 = off + 2 * (act_elems * 4) + 4096;
  const bool use_f32 = ws_size >= need_f32;

  hipMemsetAsync(cnt, 0, (size_t)N * 4, stream);
  hipMemsetAsync(psum, 0, (size_t)G * 64 * 4, stream);
  hipMemsetAsync(pcnt, 0, (size_t)G * 4, stream);

  count_kernel<<<DIV_UP(E, 256), 256, 0, stream>>>(dst, cnt, E);
  scan1_kernel<<<nchunks, 256, 0, stream>>>(cnt, rowstart, bsums, N);
  scan2_kernel<<<1, 512, 0, stream>>>(bsums, nchunks);
  scan3_kernel<<<DIV_UP(N, 256), 256, 0, stream>>>(rowstart, bsums, cursor, cnt, dinv, N, E);
  fill_kernel<<<DIV_UP(E, 256), 256, 0, stream>>>(src, dst, dinv, cursor, colw, ew, E);

  if (use_f32) {
    float* bufA = (float*)alloc(act_elems * 4);
    float* bufB = (float*)alloc(act_elems * 4);
    run_pipeline<float>(x, W1, b1, W2, b2, W3, b3, batch, dinv, rowstart, colw, ew,
                        bufA, bufB, psum, pcnt, N, stream);
  } else {
    unsigned short* bufA = (unsigned short*)alloc(act_elems * 2);
    unsigned short* bufB = (unsigned short*)alloc(act_elems * 2);
    run_pipeline<unsigned short>(x, W1, b1, W2, b2, W3, b3, batch, dinv, rowstart, colw, ew,
                                 bufA, bufB, psum, pcnt, N, stream);
  }

  heads_kernel<<<DIV_UP(5 * G, 256), 256, 0, stream>>>(psum, pcnt, Wa, ba, Wb, bb, out, G);
}

// Round 3
// 1318.954 us; speedup vs baseline: 1.0366x; 1.0366x over previous
//
#include <hip/hip_runtime.h>
#include <cstdint>
#include <cstddef>

#define DIV_UP(a, b) (((a) + (b) - 1) / (b))

typedef unsigned short u16;
typedef __attribute__((ext_vector_type(8))) short bf16x8;
typedef __attribute__((ext_vector_type(4))) float f32x4;

// ---------------- bf16 helpers (RNE) ----------------

__device__ __forceinline__ float b2f(u16 u) {
  unsigned int x = ((unsigned int)u) << 16;
  float f;
  __builtin_memcpy(&f, &x, 4);
  return f;
}
__device__ __forceinline__ u16 f2b(float f) {
  unsigned int x;
  __builtin_memcpy(&x, &f, 4);
  unsigned int r = (x + 0x7FFFu + ((x >> 16) & 1u)) >> 16;
  return (u16)r;
}

__device__ __forceinline__ float ld1(const float* p) { return *p; }
__device__ __forceinline__ float ld1(const u16* p) { return b2f(*p); }
__device__ __forceinline__ void st1(float* p, float v) { *p = v; }
__device__ __forceinline__ void st1(u16* p, float v) { *p = f2b(v); }

__device__ __forceinline__ float2 ld2(const float* p) { return *reinterpret_cast<const float2*>(p); }
__device__ __forceinline__ float2 ld2(const u16* p) {
  ushort2 u = *reinterpret_cast<const ushort2*>(p);
  return make_float2(b2f(u.x), b2f(u.y));
}
__device__ __forceinline__ void st2(float* p, float2 v) { *reinterpret_cast<float2*>(p) = v; }
__device__ __forceinline__ void st2(u16* p, float2 v) {
  ushort2 u;
  u.x = f2b(v.x);
  u.y = f2b(v.y);
  *reinterpret_cast<ushort2*>(p) = u;
}

// ---------------- CSR build ----------------

__global__ void count_kernel(const int* __restrict__ dst, int* __restrict__ cnt, int E) {
  int e = blockIdx.x * blockDim.x + threadIdx.x;
  if (e < E) atomicAdd(&cnt[dst[e]], 1);
}

__global__ void scan1_kernel(const int* __restrict__ cnt, int* __restrict__ rowstart,
                             int* __restrict__ bsums, int n) {
  __shared__ int sh[256];
  const int tid = threadIdx.x;
  const int base = blockIdx.x * 1024 + tid * 4;
  int c0 = (base + 0 < n) ? cnt[base + 0] : 0;
  int c1 = (base + 1 < n) ? cnt[base + 1] : 0;
  int c2 = (base + 2 < n) ? cnt[base + 2] : 0;
  int c3 = (base + 3 < n) ? cnt[base + 3] : 0;
  sh[tid] = c0 + c1 + c2 + c3;
  __syncthreads();
  for (int off = 1; off < 256; off <<= 1) {
    int v = (tid >= off) ? sh[tid - off] : 0;
    __syncthreads();
    sh[tid] += v;
    __syncthreads();
  }
  int excl = (tid > 0) ? sh[tid - 1] : 0;
  if (base + 0 < n) rowstart[base + 0] = excl;
  if (base + 1 < n) rowstart[base + 1] = excl + c0;
  if (base + 2 < n) rowstart[base + 2] = excl + c0 + c1;
  if (base + 3 < n) rowstart[base + 3] = excl + c0 + c1 + c2;
  if (tid == 255) bsums[blockIdx.x] = sh[255];
}

__global__ void scan2_kernel(int* __restrict__ bsums, int nb) {
  __shared__ int sh[512];
  const int tid = threadIdx.x;
  int v = (tid < nb) ? bsums[tid] : 0;
  sh[tid] = v;
  __syncthreads();
  for (int off = 1; off < 512; off <<= 1) {
    int t = (tid >= off) ? sh[tid - off] : 0;
    __syncthreads();
    sh[tid] += t;
    __syncthreads();
  }
  int excl = (tid > 0) ? sh[tid - 1] : 0;
  if (tid < nb) bsums[tid] = excl;
}

__global__ void scan3_kernel(int* __restrict__ rowstart, const int* __restrict__ bsums,
                             int* __restrict__ cursor, const int* __restrict__ cnt,
                             float* __restrict__ dinv, int n, int E) {
  int i = blockIdx.x * blockDim.x + threadIdx.x;
  if (i < n) {
    int rs = rowstart[i] + bsums[i >> 10];
    rowstart[i] = rs;
    cursor[i] = rs;
    dinv[i] = rsqrtf((float)cnt[i] + 1.0f);  // +1 for self-loop
  }
  if (i == 0) rowstart[n] = E;
}

__global__ void fill_kernel(const int* __restrict__ src, const int* __restrict__ dst,
                            const float* __restrict__ dinv, int* __restrict__ cursor,
                            int* __restrict__ col, float* __restrict__ ew, int E) {
  int e = blockIdx.x * blockDim.x + threadIdx.x;
  if (e < E) {
    int s = src[e], d = dst[e];
    int pos = atomicAdd(&cursor[d], 1);
    col[pos] = s;
    ew[pos] = dinv[s] * dinv[d];
  }
}

// ---------------- W prep: fp32 [K,NC] -> transposed split-bf16 [2][NC*K] ----------------

__global__ void prep_w(const float* __restrict__ W1, const float* __restrict__ W2,
                       const float* __restrict__ W3, u16* __restrict__ Wt1,
                       u16* __restrict__ Wt2, u16* __restrict__ Wt3) {
  int i = blockIdx.x * blockDim.x + threadIdx.x;
  float w;
  u16* dst;
  int idx, nck;
  if (i < 8192) {                       // W1 [64,128] -> Wt1 [128][64]
    int c = i >> 6, k = i & 63;
    w = W1[k * 128 + c];
    dst = Wt1; idx = i; nck = 8192;
  } else if (i < 24576) {               // W2 [128,128] -> Wt2 [128][128]
    int j = i - 8192;
    int c = j >> 7, k = j & 127;
    w = W2[k * 128 + c];
    dst = Wt2; idx = j; nck = 16384;
  } else if (i < 32768) {               // W3 [128,64] -> Wt3 [64][128]
    int j = i - 24576;
    int c = j >> 7, k = j & 127;
    w = W3[k * 64 + c];
    dst = Wt3; idx = j; nck = 8192;
  } else {
    return;
  }
  u16 hi = f2b(w);
  float lo = w - b2f(hi);
  dst[idx] = hi;
  dst[nck + idx] = f2b(lo);
}

// ---------------- aggregation: one wave (64 lanes) per node ----------------

template <int F, typename TIN, typename TOUT>  // F = 64 or 128
__global__ __launch_bounds__(256) void agg_kernel(const TIN* __restrict__ v,
                                                  const float* __restrict__ dinv,
                                                  const int* __restrict__ rowstart,
                                                  const int* __restrict__ col,
                                                  const float* __restrict__ ew,
                                                  TOUT* __restrict__ out, int n) {
  int w = (blockIdx.x * blockDim.x + threadIdx.x) >> 6;
  int lane = threadIdx.x & 63;
  if (w >= n) return;
  float di = dinv[w];
  float sw = di * di;
  int r0 = rowstart[w], r1 = rowstart[w + 1];
  if (F == 64) {
    float acc = sw * ld1(v + (size_t)w * 64 + lane);
    for (int k = r0; k < r1; ++k) {
      acc += ew[k] * ld1(v + (size_t)col[k] * 64 + lane);
    }
    st1(out + (size_t)w * 64 + lane, acc);
  } else {
    float2 a = ld2(v + (size_t)w * 128 + 2 * lane);
    float2 acc;
    acc.x = sw * a.x;
    acc.y = sw * a.y;
    for (int k = r0; k < r1; ++k) {
      float wgt = ew[k];
      float2 b = ld2(v + (size_t)col[k] * 128 + 2 * lane);
      acc.x += wgt * b.x;
      acc.y += wgt * b.y;
    }
    st2(out + (size_t)w * 128 + 2 * lane, acc);
  }
}

// layer-3 aggregation fused with bias + relu + mean-pool accumulation (F = 64)
template <typename TIN>
__global__ __launch_bounds__(256) void agg_pool_kernel(
    const TIN* __restrict__ v, const float* __restrict__ dinv,
    const int* __restrict__ rowstart, const int* __restrict__ col,
    const float* __restrict__ ew, const float* __restrict__ b3,
    const int* __restrict__ batch, float* __restrict__ psum,
    float* __restrict__ pcnt, int n) {
  int w = (blockIdx.x * blockDim.x + threadIdx.x) >> 6;
  int lane = threadIdx.x & 63;
  if (w >= n) return;
  float di = dinv[w];
  float acc = di * di * ld1(v + (size_t)w * 64 + lane);
  int r0 = rowstart[w], r1 = rowstart[w + 1];
  for (int k = r0; k < r1; ++k) {
    acc += ew[k] * ld1(v + (size_t)col[k] * 64 + lane);
  }
  float h = fmaxf(acc + b3[lane], 0.0f);
  int g = batch[w];
  atomicAdd(&psum[(size_t)g * 64 + lane], h);
  if (lane == 0) atomicAdd(&pcnt[g], 1.0f);
}

// ---------------- MFMA GEMM: [n,K]bf16 @ (Whi+Wlo) + bias (+relu) -> [n,NC]bf16 ----
// Wt is [2][NC*K] bf16 (transposed, hi then lo). Wave owns 16 rows x NC cols.
// A-frag: lane = row (l&15), k = 8*(l>>4)+j  (m97-verified layout).
// B-frag: lane = col (l&15), same k, read from LDS-staged Wt with XOR swizzle.
// C/D:    col = l&15, row = 4*(l>>4)+v  (m89/m91-verified).

template <int K, int NC, bool RELU>
__global__ __launch_bounds__(256) void gemm_mfma(const u16* __restrict__ A,
                                                 const u16* __restrict__ Wt,
                                                 const float* __restrict__ bias,
                                                 u16* __restrict__ out, int n) {
  __shared__ u16 Wl[2 * NC * K];  // <= 64 KB (K=128,NC=128 case)
  char* ldsb = (char*)Wl;
  constexpr int CH = K / 8;  // 16B chunks per row
  for (int i = threadIdx.x; i < 2 * NC * CH; i += 256) {
    int half = i / (NC * CH);
    int j = i - half * (NC * CH);
    int c = j / CH, kc = j - c * CH;
    int dstoff = half * (NC * K * 2) + c * (K * 2) + ((kc * 16) ^ ((c & 7) << 4));
    *(uint4*)(ldsb + dstoff) =
        *(const uint4*)(Wt + (size_t)half * NC * K + (size_t)c * K + kc * 8);
  }
  __syncthreads();

  const int wid = threadIdx.x >> 6;
  const int lane = threadIdx.x & 63;
  const int lr = lane & 15;
  const int lg = lane >> 4;
  const int ntiles = DIV_UP(n, 64);

  for (int t = blockIdx.x; t < ntiles; t += (int)gridDim.x) {
    const int row0 = t * 64 + wid * 16;
    int arow = row0 + lr;
    if (arow >= n) arow = n - 1;  // clamp; stores are guarded
    const u16* ap = A + (size_t)arow * K + lg * 8;

    f32x4 acc[NC / 16];
#pragma unroll
    for (int ct = 0; ct < NC / 16; ++ct) acc[ct] = {0.f, 0.f, 0.f, 0.f};

#pragma unroll
    for (int ks = 0; ks < K / 32; ++ks) {
      bf16x8 af = *(const bf16x8*)(ap + ks * 32);
#pragma unroll
      for (int ct = 0; ct < NC / 16; ++ct) {
        const int c = ct * 16 + lr;
        const int ko = ((ks * 64 + lg * 16) ^ ((c & 7) << 4));
        bf16x8 bh = *(const bf16x8*)(ldsb + c * (K * 2) + ko);
        bf16x8 bl = *(const bf16x8*)(ldsb + NC * K * 2 + c * (K * 2) + ko);
        acc[ct] = __builtin_amdgcn_mfma_f32_16x16x32_bf16(af, bh, acc[ct], 0, 0, 0);
        acc[ct] = __builtin_amdgcn_mfma_f32_16x16x32_bf16(af, bl, acc[ct], 0, 0, 0);
      }
    }

    const int orow = row0 + lg * 4;
#pragma unroll
    for (int ct = 0; ct < NC / 16; ++ct) {
      const int c = ct * 16 + lr;
      const float b = bias ? bias[c] : 0.0f;
#pragma unroll
      for (int v = 0; v < 4; ++v) {
        const int r = orow + v;
        if (r < n) {
          float o = acc[ct][v] + b;
          if (RELU) o = fmaxf(o, 0.0f);
          out[(size_t)r * NC + c] = f2b(o);
        }
      }
    }
  }
}

// ---------------- 5-task MLP heads ----------------

__global__ __launch_bounds__(256) void heads_kernel(const float* __restrict__ psum,
                                                    const float* __restrict__ pcnt,
                                                    const float* __restrict__ Wa,
                                                    const float* __restrict__ ba,
                                                    const float* __restrict__ Wb,
                                                    const float* __restrict__ bb,
                                                    float* __restrict__ outp, int G) {
  int gid = blockIdx.x * blockDim.x + threadIdx.x;
  if (gid >= 5 * G) return;
  int g = gid % G;
  int t = gid / G;
  float inv = 1.0f / fmaxf(pcnt[g], 1.0f);
  const float* Wat = Wa + (size_t)t * 64 * 32;
  float hid[32];
#pragma unroll
  for (int j = 0; j < 32; ++j) hid[j] = ba[t * 32 + j];
  for (int d = 0; d < 64; ++d) {
    float pd = psum[(size_t)g * 64 + d] * inv;
#pragma unroll
    for (int j = 0; j < 32; ++j) hid[j] += pd * Wat[d * 32 + j];
  }
  float o = bb[t];
#pragma unroll
  for (int j = 0; j < 32; ++j) o += fmaxf(hid[j], 0.0f) * Wb[t * 32 + j];
  outp[(size_t)t * G + g] = o;
}

// ---------------- launch ----------------

extern "C" void kernel_launch(void* const* d_in, const int* in_sizes, int n_in,
                              void* d_out, int out_size, void* d_ws, size_t ws_size,
                              hipStream_t stream) {
  (void)n_in;
  (void)ws_size;
  const float* x  = (const float*)d_in[0];
  const int* ei   = (const int*)d_in[1];
  const int* batch = (const int*)d_in[2];
  const float* W1 = (const float*)d_in[3];
  const float* b1 = (const float*)d_in[4];
  const float* W2 = (const float*)d_in[5];
  const float* b2 = (const float*)d_in[6];
  const float* W3 = (const float*)d_in[7];
  const float* b3 = (const float*)d_in[8];
  const float* Wa = (const float*)d_in[9];
  const float* ba = (const float*)d_in[10];
  const float* Wb = (const float*)d_in[11];
  const float* bb = (const float*)d_in[12];
  float* out = (float*)d_out;

  const int N = in_sizes[0] / 64;
  const int E = in_sizes[1] / 2;
  const int G = out_size / 5;
  const int* src = ei;
  const int* dst = ei + E;

  char* ws = (char*)d_ws;
  size_t off = 0;
  auto alloc = [&](size_t bytes) -> char* {
    char* p = ws + off;
    off = (off + bytes + 255) & ~(size_t)255;
    return p;
  };
  int* cnt      = (int*)alloc((size_t)N * 4);
  int* rowstart = (int*)alloc((size_t)(N + 1) * 4);
  int* cursor   = (int*)alloc((size_t)N * 4);
  int* colw     = (int*)alloc((size_t)E * 4);
  float* ew     = (float*)alloc((size_t)E * 4);
  float* dinv   = (float*)alloc((size_t)N * 4);
  const int nchunks = DIV_UP(N, 1024);  // 391 for N=400000 (<= 512)
  int* bsums    = (int*)alloc((size_t)nchunks * 4);
  float* psum   = (float*)alloc((size_t)G * 64 * 4);
  float* pcnt   = (float*)alloc((size_t)G * 4);
  u16* Wt1      = (u16*)alloc(2 * 8192 * 2);
  u16* Wt2      = (u16*)alloc(2 * 16384 * 2);
  u16* Wt3      = (u16*)alloc(2 * 8192 * 2);
  const size_t act_elems = (size_t)N * 128;
  u16* bufA     = (u16*)alloc(act_elems * 2);
  u16* bufB     = (u16*)alloc(act_elems * 2);

  hipMemsetAsync(cnt, 0, (size_t)N * 4, stream);
  hipMemsetAsync(psum, 0, (size_t)G * 64 * 4, stream);
  hipMemsetAsync(pcnt, 0, (size_t)G * 4, stream);

  count_kernel<<<DIV_UP(E, 256), 256, 0, stream>>>(dst, cnt, E);
  scan1_kernel<<<nchunks, 256, 0, stream>>>(cnt, rowstart, bsums, N);
  scan2_kernel<<<1, 512, 0, stream>>>(bsums, nchunks);
  scan3_kernel<<<DIV_UP(N, 256), 256, 0, stream>>>(rowstart, bsums, cursor, cnt, dinv, N, E);
  fill_kernel<<<DIV_UP(E, 256), 256, 0, stream>>>(src, dst, dinv, cursor, colw, ew, E);
  prep_w<<<128, 256, 0, stream>>>(W1, W2, W3, Wt1, Wt2, Wt3);

  const int ntiles = DIV_UP(N, 64);
  // t1 [N,64] in bufB; h1 [N,128] in bufA; t2 [N,128] in bufB; h2 [N,128] in bufA;
  // hw3 [N,64] in bufB.
  agg_kernel<64, float, u16><<<DIV_UP(N, 4), 256, 0, stream>>>(x, dinv, rowstart, colw, ew, bufB, N);
  gemm_mfma<64, 128, true><<<ntiles, 256, 0, stream>>>(bufB, Wt1, b1, bufA, N);
  agg_kernel<128, u16, u16><<<DIV_UP(N, 4), 256, 0, stream>>>(bufA, dinv, rowstart, colw, ew, bufB, N);
  gemm_mfma<128, 128, true><<<ntiles, 256, 0, stream>>>(bufB, Wt2, b2, bufA, N);
  gemm_mfma<128, 64, false><<<ntiles, 256, 0, stream>>>(bufA, Wt3, nullptr, bufB, N);
  agg_pool_kernel<u16><<<DIV_UP(N, 4), 256, 0, stream>>>(bufB, dinv, rowstart, colw, ew, b3,
                                                         batch, psum, pcnt, N);
  heads_kernel<<<DIV_UP(5 * G, 256), 256, 0, stream>>>(psum, pcnt, Wa, ba, Wb, bb, out, G);
}

// Round 4
// 971.552 us; speedup vs baseline: 1.4073x; 1.3576x over previous
//
#include <hip/hip_runtime.h>
#include <cstdint>
#include <cstddef>

#define DIV_UP(a, b) (((a) + (b) - 1) / (b))

typedef unsigned short u16;
typedef __attribute__((ext_vector_type(8))) short bf16x8;
typedef __attribute__((ext_vector_type(4))) float f32x4;

// ---------------- bf16 helpers (RNE) ----------------

__device__ __forceinline__ float b2f(u16 u) {
  unsigned int x = ((unsigned int)u) << 16;
  float f;
  __builtin_memcpy(&f, &x, 4);
  return f;
}
__device__ __forceinline__ u16 f2b(float f) {
  unsigned int x;
  __builtin_memcpy(&x, &f, 4);
  unsigned int r = (x + 0x7FFFu + ((x >> 16) & 1u)) >> 16;
  return (u16)r;
}

__device__ __forceinline__ float ld1(const float* p) { return *p; }
__device__ __forceinline__ float ld1(const u16* p) { return b2f(*p); }
__device__ __forceinline__ void st1(float* p, float v) { *p = v; }
__device__ __forceinline__ void st1(u16* p, float v) { *p = f2b(v); }

__device__ __forceinline__ float2 ld2(const float* p) { return *reinterpret_cast<const float2*>(p); }
__device__ __forceinline__ float2 ld2(const u16* p) {
  ushort2 u = *reinterpret_cast<const ushort2*>(p);
  return make_float2(b2f(u.x), b2f(u.y));
}
__device__ __forceinline__ void st2(float* p, float2 v) { *reinterpret_cast<float2*>(p) = v; }
__device__ __forceinline__ void st2(u16* p, float2 v) {
  ushort2 u;
  u.x = f2b(v.x);
  u.y = f2b(v.y);
  *reinterpret_cast<ushort2*>(p) = u;
}

// ---------------- CSR build ----------------

__global__ void count_kernel(const int* __restrict__ dst, int* __restrict__ cnt, int E) {
  int e = blockIdx.x * blockDim.x + threadIdx.x;
  if (e < E) atomicAdd(&cnt[dst[e]], 1);
}

__global__ void scan1_kernel(const int* __restrict__ cnt, int* __restrict__ rowstart,
                             int* __restrict__ bsums, int n) {
  __shared__ int sh[256];
  const int tid = threadIdx.x;
  const int base = blockIdx.x * 1024 + tid * 4;
  int c0 = (base + 0 < n) ? cnt[base + 0] : 0;
  int c1 = (base + 1 < n) ? cnt[base + 1] : 0;
  int c2 = (base + 2 < n) ? cnt[base + 2] : 0;
  int c3 = (base + 3 < n) ? cnt[base + 3] : 0;
  sh[tid] = c0 + c1 + c2 + c3;
  __syncthreads();
  for (int off = 1; off < 256; off <<= 1) {
    int v = (tid >= off) ? sh[tid - off] : 0;
    __syncthreads();
    sh[tid] += v;
    __syncthreads();
  }
  int excl = (tid > 0) ? sh[tid - 1] : 0;
  if (base + 0 < n) rowstart[base + 0] = excl;
  if (base + 1 < n) rowstart[base + 1] = excl + c0;
  if (base + 2 < n) rowstart[base + 2] = excl + c0 + c1;
  if (base + 3 < n) rowstart[base + 3] = excl + c0 + c1 + c2;
  if (tid == 255) bsums[blockIdx.x] = sh[255];
}

__global__ void scan2_kernel(int* __restrict__ bsums, int nb) {
  __shared__ int sh[512];
  const int tid = threadIdx.x;
  int v = (tid < nb) ? bsums[tid] : 0;
  sh[tid] = v;
  __syncthreads();
  for (int off = 1; off < 512; off <<= 1) {
    int t = (tid >= off) ? sh[tid - off] : 0;
    __syncthreads();
    sh[tid] += t;
    __syncthreads();
  }
  int excl = (tid > 0) ? sh[tid - 1] : 0;
  if (tid < nb) bsums[tid] = excl;
}

__global__ void scan3_kernel(int* __restrict__ rowstart, const int* __restrict__ bsums,
                             int* __restrict__ cursor, const int* __restrict__ cnt,
                             float* __restrict__ dinv, int n, int E) {
  int i = blockIdx.x * blockDim.x + threadIdx.x;
  if (i < n) {
    int rs = rowstart[i] + bsums[i >> 10];
    rowstart[i] = rs;
    cursor[i] = rs;
    dinv[i] = rsqrtf((float)cnt[i] + 1.0f);  // +1 for self-loop
  }
  if (i == 0) rowstart[n] = E;
}

__global__ void fill_kernel(const int* __restrict__ src, const int* __restrict__ dst,
                            const float* __restrict__ dinv, int* __restrict__ cursor,
                            int* __restrict__ col, float* __restrict__ ew, int E) {
  int e = blockIdx.x * blockDim.x + threadIdx.x;
  if (e < E) {
    int s = src[e], d = dst[e];
    int pos = atomicAdd(&cursor[d], 1);
    col[pos] = s;
    ew[pos] = dinv[s] * dinv[d];
  }
}

// ---------------- W prep: fp32 [K,NC] -> transposed split-bf16 [2][NC*K] ----------------

__global__ void prep_w(const float* __restrict__ W1, const float* __restrict__ W2,
                       const float* __restrict__ W3, u16* __restrict__ Wt1,
                       u16* __restrict__ Wt2, u16* __restrict__ Wt3) {
  int i = blockIdx.x * blockDim.x + threadIdx.x;
  float w;
  u16* dst;
  int idx, nck;
  if (i < 8192) {                       // W1 [64,128] -> Wt1 [128][64]
    int c = i >> 6, k = i & 63;
    w = W1[k * 128 + c];
    dst = Wt1; idx = i; nck = 8192;
  } else if (i < 24576) {               // W2 [128,128] -> Wt2 [128][128]
    int j = i - 8192;
    int c = j >> 7, k = j & 127;
    w = W2[k * 128 + c];
    dst = Wt2; idx = j; nck = 16384;
  } else if (i < 32768) {               // W3 [128,64] -> Wt3 [64][128]
    int j = i - 24576;
    int c = j >> 7, k = j & 127;
    w = W3[k * 64 + c];
    dst = Wt3; idx = j; nck = 8192;
  } else {
    return;
  }
  u16 hi = f2b(w);
  float lo = w - b2f(hi);
  dst[idx] = hi;
  dst[nck + idx] = f2b(lo);
}

// ---------------- aggregation: one wave per node, 4-deep gather pipeline ----------------

template <int F, bool BR, typename TIN, typename TOUT>  // F = 64 or 128
__global__ __launch_bounds__(256) void agg_kernel(const TIN* __restrict__ v,
                                                  const float* __restrict__ dinv,
                                                  const int* __restrict__ rowstart,
                                                  const int* __restrict__ col,
                                                  const float* __restrict__ ew,
                                                  const float* __restrict__ bias,
                                                  TOUT* __restrict__ out, int n) {
  int w = (blockIdx.x * blockDim.x + threadIdx.x) >> 6;
  int lane = threadIdx.x & 63;
  if (w >= n) return;
  float di = dinv[w];
  float sw = di * di;
  int r0 = rowstart[w], r1 = rowstart[w + 1];
  if (F == 64) {
    float acc = sw * ld1(v + (size_t)w * 64 + lane);
    float a0 = 0.f, a1 = 0.f, a2 = 0.f, a3 = 0.f;
    int k = r0;
    for (; k + 4 <= r1; k += 4) {
      int c0 = col[k], c1 = col[k + 1], c2 = col[k + 2], c3 = col[k + 3];
      float w0 = ew[k], w1 = ew[k + 1], w2 = ew[k + 2], w3 = ew[k + 3];
      a0 += w0 * ld1(v + (size_t)c0 * 64 + lane);
      a1 += w1 * ld1(v + (size_t)c1 * 64 + lane);
      a2 += w2 * ld1(v + (size_t)c2 * 64 + lane);
      a3 += w3 * ld1(v + (size_t)c3 * 64 + lane);
    }
    for (; k < r1; ++k) acc += ew[k] * ld1(v + (size_t)col[k] * 64 + lane);
    acc += (a0 + a1) + (a2 + a3);
    if (BR) acc = fmaxf(acc + bias[lane], 0.0f);
    st1(out + (size_t)w * 64 + lane, acc);
  } else {
    float2 a = ld2(v + (size_t)w * 128 + 2 * lane);
    float2 acc = make_float2(sw * a.x, sw * a.y);
    float2 p0 = make_float2(0.f, 0.f), p1 = p0, p2 = p0, p3 = p0;
    int k = r0;
    for (; k + 4 <= r1; k += 4) {
      int c0 = col[k], c1 = col[k + 1], c2 = col[k + 2], c3 = col[k + 3];
      float w0 = ew[k], w1 = ew[k + 1], w2 = ew[k + 2], w3 = ew[k + 3];
      float2 b0 = ld2(v + (size_t)c0 * 128 + 2 * lane);
      float2 b1 = ld2(v + (size_t)c1 * 128 + 2 * lane);
      float2 b2 = ld2(v + (size_t)c2 * 128 + 2 * lane);
      float2 b3 = ld2(v + (size_t)c3 * 128 + 2 * lane);
      p0.x += w0 * b0.x; p0.y += w0 * b0.y;
      p1.x += w1 * b1.x; p1.y += w1 * b1.y;
      p2.x += w2 * b2.x; p2.y += w2 * b2.y;
      p3.x += w3 * b3.x; p3.y += w3 * b3.y;
    }
    for (; k < r1; ++k) {
      float wgt = ew[k];
      float2 b = ld2(v + (size_t)col[k] * 128 + 2 * lane);
      acc.x += wgt * b.x;
      acc.y += wgt * b.y;
    }
    acc.x += (p0.x + p1.x) + (p2.x + p3.x);
    acc.y += (p0.y + p1.y) + (p2.y + p3.y);
    st2(out + (size_t)w * 128 + 2 * lane, acc);
  }
}

// ---------------- graph boundaries (batch is sorted) + segmented mean pool ----------------

__global__ void gbounds_kernel(const int* __restrict__ batch, int* __restrict__ gstart,
                               int N, int G) {
  int g = blockIdx.x * blockDim.x + threadIdx.x;
  if (g > G) return;
  int lo = 0, hi = N;
  while (lo < hi) {
    int mid = (lo + hi) >> 1;
    if (batch[mid] < g) lo = mid + 1; else hi = mid;
  }
  gstart[g] = lo;
}

// one wave per graph; lane = feature; nodes of graph are contiguous rows
__global__ __launch_bounds__(256) void pool_kernel(const u16* __restrict__ h3,
                                                   const int* __restrict__ gstart,
                                                   float* __restrict__ pooled, int G) {
  int g = (blockIdx.x * blockDim.x + threadIdx.x) >> 6;
  int lane = threadIdx.x & 63;
  if (g >= G) return;
  int s = gstart[g], e = gstart[g + 1];
  float a0 = 0.f, a1 = 0.f, a2 = 0.f, a3 = 0.f;
  int i = s;
  for (; i + 4 <= e; i += 4) {
    a0 += b2f(h3[(size_t)(i + 0) * 64 + lane]);
    a1 += b2f(h3[(size_t)(i + 1) * 64 + lane]);
    a2 += b2f(h3[(size_t)(i + 2) * 64 + lane]);
    a3 += b2f(h3[(size_t)(i + 3) * 64 + lane]);
  }
  for (; i < e; ++i) a0 += b2f(h3[(size_t)i * 64 + lane]);
  float acc = (a0 + a1) + (a2 + a3);
  pooled[(size_t)g * 64 + lane] = acc / fmaxf((float)(e - s), 1.0f);
}

// ---------------- MFMA GEMM: [n,K]bf16 @ (Whi+Wlo) + bias (+relu) -> [n,NC]bf16 ----
// Wt is [2][NC*K] bf16 (transposed, hi then lo). Wave owns 16 rows x NC cols.
// Grid-stride over 64-row tiles; W staged in LDS once per block (XOR-swizzled).

template <int K, int NC, bool RELU>
__global__ __launch_bounds__(256) void gemm_mfma(const u16* __restrict__ A,
                                                 const u16* __restrict__ Wt,
                                                 const float* __restrict__ bias,
                                                 u16* __restrict__ out, int n) {
  __shared__ u16 Wl[2 * NC * K];  // <= 64 KB (K=128,NC=128 case)
  char* ldsb = (char*)Wl;
  constexpr int CH = K / 8;  // 16B chunks per row
  for (int i = threadIdx.x; i < 2 * NC * CH; i += 256) {
    int half = i / (NC * CH);
    int j = i - half * (NC * CH);
    int c = j / CH, kc = j - c * CH;
    int dstoff = half * (NC * K * 2) + c * (K * 2) + ((kc * 16) ^ ((c & 7) << 4));
    *(uint4*)(ldsb + dstoff) =
        *(const uint4*)(Wt + (size_t)half * NC * K + (size_t)c * K + kc * 8);
  }
  __syncthreads();

  const int wid = threadIdx.x >> 6;
  const int lane = threadIdx.x & 63;
  const int lr = lane & 15;
  const int lg = lane >> 4;
  const int ntiles = DIV_UP(n, 64);

  for (int t = blockIdx.x; t < ntiles; t += (int)gridDim.x) {
    const int row0 = t * 64 + wid * 16;
    int arow = row0 + lr;
    if (arow >= n) arow = n - 1;  // clamp; stores are guarded
    const u16* ap = A + (size_t)arow * K + lg * 8;

    f32x4 acc[NC / 16];
#pragma unroll
    for (int ct = 0; ct < NC / 16; ++ct) acc[ct] = {0.f, 0.f, 0.f, 0.f};

#pragma unroll
    for (int ks = 0; ks < K / 32; ++ks) {
      bf16x8 af = *(const bf16x8*)(ap + ks * 32);
#pragma unroll
      for (int ct = 0; ct < NC / 16; ++ct) {
        const int c = ct * 16 + lr;
        const int ko = ((ks * 64 + lg * 16) ^ ((c & 7) << 4));
        bf16x8 bh = *(const bf16x8*)(ldsb + c * (K * 2) + ko);
        bf16x8 bl = *(const bf16x8*)(ldsb + NC * K * 2 + c * (K * 2) + ko);
        acc[ct] = __builtin_amdgcn_mfma_f32_16x16x32_bf16(af, bh, acc[ct], 0, 0, 0);
        acc[ct] = __builtin_amdgcn_mfma_f32_16x16x32_bf16(af, bl, acc[ct], 0, 0, 0);
      }
    }

    const int orow = row0 + lg * 4;
#pragma unroll
    for (int ct = 0; ct < NC / 16; ++ct) {
      const int c = ct * 16 + lr;
      const float b = bias ? bias[c] : 0.0f;
#pragma unroll
      for (int v = 0; v < 4; ++v) {
        const int r = orow + v;
        if (r < n) {
          float o = acc[ct][v] + b;
          if (RELU) o = fmaxf(o, 0.0f);
          out[(size_t)r * NC + c] = f2b(o);
        }
      }
    }
  }
}

// ---------------- 5-task MLP heads ----------------

__global__ __launch_bounds__(256) void heads_kernel(const float* __restrict__ pooled,
                                                    const float* __restrict__ Wa,
                                                    const float* __restrict__ ba,
                                                    const float* __restrict__ Wb,
                                                    const float* __restrict__ bb,
                                                    float* __restrict__ outp, int G) {
  int gid = blockIdx.x * blockDim.x + threadIdx.x;
  if (gid >= 5 * G) return;
  int g = gid % G;
  int t = gid / G;
  const float* Wat = Wa + (size_t)t * 64 * 32;
  float hid[32];
#pragma unroll
  for (int j = 0; j < 32; ++j) hid[j] = ba[t * 32 + j];
  for (int d = 0; d < 64; ++d) {
    float pd = pooled[(size_t)g * 64 + d];
#pragma unroll
    for (int j = 0; j < 32; ++j) hid[j] += pd * Wat[d * 32 + j];
  }
  float o = bb[t];
#pragma unroll
  for (int j = 0; j < 32; ++j) o += fmaxf(hid[j], 0.0f) * Wb[t * 32 + j];
  outp[(size_t)t * G + g] = o;
}

// ---------------- launch ----------------

extern "C" void kernel_launch(void* const* d_in, const int* in_sizes, int n_in,
                              void* d_out, int out_size, void* d_ws, size_t ws_size,
                              hipStream_t stream) {
  (void)n_in;
  (void)ws_size;
  const float* x  = (const float*)d_in[0];
  const int* ei   = (const int*)d_in[1];
  const int* batch = (const int*)d_in[2];
  const float* W1 = (const float*)d_in[3];
  const float* b1 = (const float*)d_in[4];
  const float* W2 = (const float*)d_in[5];
  const float* b2 = (const float*)d_in[6];
  const float* W3 = (const float*)d_in[7];
  const float* b3 = (const float*)d_in[8];
  const float* Wa = (const float*)d_in[9];
  const float* ba = (const float*)d_in[10];
  const float* Wb = (const float*)d_in[11];
  const float* bb = (const float*)d_in[12];
  float* out = (float*)d_out;

  const int N = in_sizes[0] / 64;
  const int E = in_sizes[1] / 2;
  const int G = out_size / 5;
  const int* src = ei;
  const int* dst = ei + E;

  char* ws = (char*)d_ws;
  size_t off = 0;
  auto alloc = [&](size_t bytes) -> char* {
    char* p = ws + off;
    off = (off + bytes + 255) & ~(size_t)255;
    return p;
  };
  int* cnt      = (int*)alloc((size_t)N * 4);
  int* rowstart = (int*)alloc((size_t)(N + 1) * 4);
  int* cursor   = (int*)alloc((size_t)N * 4);
  int* colw     = (int*)alloc((size_t)E * 4);
  float* ew     = (float*)alloc((size_t)E * 4);
  float* dinv   = (float*)alloc((size_t)N * 4);
  const int nchunks = DIV_UP(N, 1024);  // 391 for N=400000 (<= 512)
  int* bsums    = (int*)alloc((size_t)nchunks * 4);
  int* gstart   = (int*)alloc((size_t)(G + 1) * 4);
  float* pooled = (float*)alloc((size_t)G * 64 * 4);
  u16* Wt1      = (u16*)alloc(2 * 8192 * 2);
  u16* Wt2      = (u16*)alloc(2 * 16384 * 2);
  u16* Wt3      = (u16*)alloc(2 * 8192 * 2);
  const size_t act_elems = (size_t)N * 128;
  u16* bufA     = (u16*)alloc(act_elems * 2);
  u16* bufB     = (u16*)alloc(act_elems * 2);

  hipMemsetAsync(cnt, 0, (size_t)N * 4, stream);

  count_kernel<<<DIV_UP(E, 256), 256, 0, stream>>>(dst, cnt, E);
  scan1_kernel<<<nchunks, 256, 0, stream>>>(cnt, rowstart, bsums, N);
  scan2_kernel<<<1, 512, 0, stream>>>(bsums, nchunks);
  scan3_kernel<<<DIV_UP(N, 256), 256, 0, stream>>>(rowstart, bsums, cursor, cnt, dinv, N, E);
  fill_kernel<<<DIV_UP(E, 256), 256, 0, stream>>>(src, dst, dinv, cursor, colw, ew, E);
  prep_w<<<128, 256, 0, stream>>>(W1, W2, W3, Wt1, Wt2, Wt3);
  gbounds_kernel<<<DIV_UP(G + 1, 256), 256, 0, stream>>>(batch, gstart, N, G);

  // t1 [N,64] in bufB; h1 [N,128] in bufA; t2 [N,128] in bufB; h2 [N,128] in bufA;
  // hw3 [N,64] in bufB; h3 [N,64] in bufA.
  agg_kernel<64, false, float, u16><<<DIV_UP(N, 4), 256, 0, stream>>>(
      x, dinv, rowstart, colw, ew, nullptr, bufB, N);
  gemm_mfma<64, 128, true><<<512, 256, 0, stream>>>(bufB, Wt1, b1, bufA, N);
  agg_kernel<128, false, u16, u16><<<DIV_UP(N, 4), 256, 0, stream>>>(
      bufA, dinv, rowstart, colw, ew, nullptr, bufB, N);
  gemm_mfma<128, 128, true><<<512, 256, 0, stream>>>(bufB, Wt2, b2, bufA, N);
  gemm_mfma<128, 64, false><<<512, 256, 0, stream>>>(bufA, Wt3, nullptr, bufB, N);
  agg_kernel<64, true, u16, u16><<<DIV_UP(N, 4), 256, 0, stream>>>(
      bufB, dinv, rowstart, colw, ew, b3, bufA, N);
  pool_kernel<<<DIV_UP(G, 4), 256, 0, stream>>>(bufA, gstart, pooled, G);
  heads_kernel<<<DIV_UP(5 * G, 256), 256, 0, stream>>>(pooled, Wa, ba, Wb, bb, out, G);
}

// Round 5
// 934.538 us; speedup vs baseline: 1.4631x; 1.0396x over previous
//
#include <hip/hip_runtime.h>
#include <cstdint>
#include <cstddef>

#define DIV_UP(a, b) (((a) + (b) - 1) / (b))

typedef unsigned short u16;
typedef __attribute__((ext_vector_type(8))) short bf16x8;
typedef __attribute__((ext_vector_type(4))) float f32x4;

// ---------------- bf16 helpers (RNE) ----------------

__device__ __forceinline__ float b2f(u16 u) {
  unsigned int x = ((unsigned int)u) << 16;
  float f;
  __builtin_memcpy(&f, &x, 4);
  return f;
}
__device__ __forceinline__ u16 f2b(float f) {
  unsigned int x;
  __builtin_memcpy(&x, &f, 4);
  unsigned int r = (x + 0x7FFFu + ((x >> 16) & 1u)) >> 16;
  return (u16)r;
}

__device__ __forceinline__ float2 ld2b(const u16* p) {
  ushort2 u = *reinterpret_cast<const ushort2*>(p);
  return make_float2(b2f(u.x), b2f(u.y));
}
__device__ __forceinline__ void st2b(u16* p, float2 v) {
  ushort2 u;
  u.x = f2b(v.x);
  u.y = f2b(v.y);
  *reinterpret_cast<ushort2*>(p) = u;
}
__device__ __forceinline__ float4 ld4b(const u16* p) {
  ushort4 u = *reinterpret_cast<const ushort4*>(p);
  return make_float4(b2f(u.x), b2f(u.y), b2f(u.z), b2f(u.w));
}
__device__ __forceinline__ void st4b(u16* p, float4 v) {
  ushort4 u;
  u.x = f2b(v.x);
  u.y = f2b(v.y);
  u.z = f2b(v.z);
  u.w = f2b(v.w);
  *reinterpret_cast<ushort4*>(p) = u;
}

// ---------------- CSR build ----------------

__global__ void count_kernel(const int* __restrict__ dst, int* __restrict__ cnt, int E) {
  int e = blockIdx.x * blockDim.x + threadIdx.x;
  if (e < E) atomicAdd(&cnt[dst[e]], 1);
}

__global__ void scan1_kernel(const int* __restrict__ cnt, int* __restrict__ rowstart,
                             int* __restrict__ bsums, int n) {
  __shared__ int sh[256];
  const int tid = threadIdx.x;
  const int base = blockIdx.x * 1024 + tid * 4;
  int c0 = (base + 0 < n) ? cnt[base + 0] : 0;
  int c1 = (base + 1 < n) ? cnt[base + 1] : 0;
  int c2 = (base + 2 < n) ? cnt[base + 2] : 0;
  int c3 = (base + 3 < n) ? cnt[base + 3] : 0;
  sh[tid] = c0 + c1 + c2 + c3;
  __syncthreads();
  for (int off = 1; off < 256; off <<= 1) {
    int v = (tid >= off) ? sh[tid - off] : 0;
    __syncthreads();
    sh[tid] += v;
    __syncthreads();
  }
  int excl = (tid > 0) ? sh[tid - 1] : 0;
  if (base + 0 < n) rowstart[base + 0] = excl;
  if (base + 1 < n) rowstart[base + 1] = excl + c0;
  if (base + 2 < n) rowstart[base + 2] = excl + c0 + c1;
  if (base + 3 < n) rowstart[base + 3] = excl + c0 + c1 + c2;
  if (tid == 255) bsums[blockIdx.x] = sh[255];
}

__global__ void scan2_kernel(int* __restrict__ bsums, int nb) {
  __shared__ int sh[512];
  const int tid = threadIdx.x;
  int v = (tid < nb) ? bsums[tid] : 0;
  sh[tid] = v;
  __syncthreads();
  for (int off = 1; off < 512; off <<= 1) {
    int t = (tid >= off) ? sh[tid - off] : 0;
    __syncthreads();
    sh[tid] += t;
    __syncthreads();
  }
  int excl = (tid > 0) ? sh[tid - 1] : 0;
  if (tid < nb) bsums[tid] = excl;
}

__global__ void scan3_kernel(int* __restrict__ rowstart, const int* __restrict__ bsums,
                             int* __restrict__ cursor, const int* __restrict__ cnt,
                             float* __restrict__ dinv, int n, int E) {
  int i = blockIdx.x * blockDim.x + threadIdx.x;
  if (i < n) {
    int rs = rowstart[i] + bsums[i >> 10];
    rowstart[i] = rs;
    cursor[i] = rs;
    dinv[i] = rsqrtf((float)cnt[i] + 1.0f);  // +1 for self-loop
  }
  if (i == 0) rowstart[n] = E;
}

__global__ void fill_kernel(const int* __restrict__ src, const int* __restrict__ dst,
                            const float* __restrict__ dinv, int* __restrict__ cursor,
                            int* __restrict__ col, float* __restrict__ ew, int E) {
  int e = blockIdx.x * blockDim.x + threadIdx.x;
  if (e < E) {
    int s = src[e], d = dst[e];
    int pos = atomicAdd(&cursor[d], 1);
    col[pos] = s;
    ew[pos] = dinv[s] * dinv[d];
  }
}

// ---------------- W prep: fp32 [K,NC] -> transposed split-bf16 [2][NC*K] ----------------

__global__ void prep_w(const float* __restrict__ W1, const float* __restrict__ W2,
                       const float* __restrict__ W3, u16* __restrict__ Wt1,
                       u16* __restrict__ Wt2, u16* __restrict__ Wt3) {
  int i = blockIdx.x * blockDim.x + threadIdx.x;
  float w;
  u16* dst;
  int idx, nck;
  if (i < 8192) {                       // W1 [64,128] -> Wt1 [128][64]
    int c = i >> 6, k = i & 63;
    w = W1[k * 128 + c];
    dst = Wt1; idx = i; nck = 8192;
  } else if (i < 24576) {               // W2 [128,128] -> Wt2 [128][128]
    int j = i - 8192;
    int c = j >> 7, k = j & 127;
    w = W2[k * 128 + c];
    dst = Wt2; idx = j; nck = 16384;
  } else if (i < 32768) {               // W3 [128,64] -> Wt3 [64][128]
    int j = i - 24576;
    int c = j >> 7, k = j & 127;
    w = W3[k * 64 + c];
    dst = Wt3; idx = j; nck = 8192;
  } else {
    return;
  }
  u16 hi = f2b(w);
  float lo = w - b2f(hi);
  dst[idx] = hi;
  dst[nck + idx] = f2b(lo);
}

// ---------------- x fp32 -> bf16 ----------------

__global__ void conv_x(const float* __restrict__ x, u16* __restrict__ xb, int n8) {
  int i = blockIdx.x * blockDim.x + threadIdx.x;
  if (i >= n8) return;
  const float4* p = reinterpret_cast<const float4*>(x) + (size_t)i * 2;
  float4 a = p[0], b = p[1];
  st4b(xb + (size_t)i * 8, a);
  st4b(xb + (size_t)i * 8 + 4, b);
}

// ---------------- aggregation: half-wave (32 lanes) per node, 4-deep pipeline ----------------

template <int F, bool BR>  // F = 64 or 128; bf16 in/out
__global__ __launch_bounds__(256) void agg_kernel(const u16* __restrict__ v,
                                                  const float* __restrict__ dinv,
                                                  const int* __restrict__ rowstart,
                                                  const int* __restrict__ col,
                                                  const float* __restrict__ ew,
                                                  const float* __restrict__ bias,
                                                  u16* __restrict__ out, int n) {
  int node = (blockIdx.x * blockDim.x + threadIdx.x) >> 5;
  int l = threadIdx.x & 31;
  if (node >= n) return;
  float di = dinv[node];
  float sw = di * di;
  int r0 = rowstart[node], r1 = rowstart[node + 1];
  if (F == 64) {
    float2 s = ld2b(v + (size_t)node * 64 + l * 2);
    float2 acc = make_float2(sw * s.x, sw * s.y);
    float2 p0 = make_float2(0.f, 0.f), p1 = p0, p2 = p0, p3 = p0;
    int k = r0;
    for (; k + 4 <= r1; k += 4) {
      int c0 = col[k], c1 = col[k + 1], c2 = col[k + 2], c3 = col[k + 3];
      float w0 = ew[k], w1 = ew[k + 1], w2 = ew[k + 2], w3 = ew[k + 3];
      float2 b0 = ld2b(v + (size_t)c0 * 64 + l * 2);
      float2 b1 = ld2b(v + (size_t)c1 * 64 + l * 2);
      float2 b2 = ld2b(v + (size_t)c2 * 64 + l * 2);
      float2 b3 = ld2b(v + (size_t)c3 * 64 + l * 2);
      p0.x += w0 * b0.x; p0.y += w0 * b0.y;
      p1.x += w1 * b1.x; p1.y += w1 * b1.y;
      p2.x += w2 * b2.x; p2.y += w2 * b2.y;
      p3.x += w3 * b3.x; p3.y += w3 * b3.y;
    }
    for (; k < r1; ++k) {
      float wgt = ew[k];
      float2 b = ld2b(v + (size_t)col[k] * 64 + l * 2);
      acc.x += wgt * b.x;
      acc.y += wgt * b.y;
    }
    acc.x += (p0.x + p1.x) + (p2.x + p3.x);
    acc.y += (p0.y + p1.y) + (p2.y + p3.y);
    if (BR) {
      acc.x = fmaxf(acc.x + bias[l * 2 + 0], 0.0f);
      acc.y = fmaxf(acc.y + bias[l * 2 + 1], 0.0f);
    }
    st2b(out + (size_t)node * 64 + l * 2, acc);
  } else {
    float4 s = ld4b(v + (size_t)node * 128 + l * 4);
    float4 acc = make_float4(sw * s.x, sw * s.y, sw * s.z, sw * s.w);
    float4 p0 = make_float4(0.f, 0.f, 0.f, 0.f), p1 = p0, p2 = p0, p3 = p0;
    int k = r0;
    for (; k + 4 <= r1; k += 4) {
      int c0 = col[k], c1 = col[k + 1], c2 = col[k + 2], c3 = col[k + 3];
      float w0 = ew[k], w1 = ew[k + 1], w2 = ew[k + 2], w3 = ew[k + 3];
      float4 b0 = ld4b(v + (size_t)c0 * 128 + l * 4);
      float4 b1 = ld4b(v + (size_t)c1 * 128 + l * 4);
      float4 b2 = ld4b(v + (size_t)c2 * 128 + l * 4);
      float4 b3 = ld4b(v + (size_t)c3 * 128 + l * 4);
      p0.x += w0 * b0.x; p0.y += w0 * b0.y; p0.z += w0 * b0.z; p0.w += w0 * b0.w;
      p1.x += w1 * b1.x; p1.y += w1 * b1.y; p1.z += w1 * b1.z; p1.w += w1 * b1.w;
      p2.x += w2 * b2.x; p2.y += w2 * b2.y; p2.z += w2 * b2.z; p2.w += w2 * b2.w;
      p3.x += w3 * b3.x; p3.y += w3 * b3.y; p3.z += w3 * b3.z; p3.w += w3 * b3.w;
    }
    for (; k < r1; ++k) {
      float wgt = ew[k];
      float4 b = ld4b(v + (size_t)col[k] * 128 + l * 4);
      acc.x += wgt * b.x; acc.y += wgt * b.y; acc.z += wgt * b.z; acc.w += wgt * b.w;
    }
    acc.x += (p0.x + p1.x) + (p2.x + p3.x);
    acc.y += (p0.y + p1.y) + (p2.y + p3.y);
    acc.z += (p0.z + p1.z) + (p2.z + p3.z);
    acc.w += (p0.w + p1.w) + (p2.w + p3.w);
    st4b(out + (size_t)node * 128 + l * 4, acc);
  }
}

// ---------------- graph boundaries (batch sorted) + segmented mean pool ----------------

__global__ void gbounds_kernel(const int* __restrict__ batch, int* __restrict__ gstart,
                               int N, int G) {
  int g = blockIdx.x * blockDim.x + threadIdx.x;
  if (g > G) return;
  int lo = 0, hi = N;
  while (lo < hi) {
    int mid = (lo + hi) >> 1;
    if (batch[mid] < g) lo = mid + 1; else hi = mid;
  }
  gstart[g] = lo;
}

__global__ __launch_bounds__(256) void pool_kernel(const u16* __restrict__ h3,
                                                   const int* __restrict__ gstart,
                                                   float* __restrict__ pooled, int G) {
  int g = (blockIdx.x * blockDim.x + threadIdx.x) >> 6;
  int lane = threadIdx.x & 63;
  if (g >= G) return;
  int s = gstart[g], e = gstart[g + 1];
  float a0 = 0.f, a1 = 0.f, a2 = 0.f, a3 = 0.f;
  int i = s;
  for (; i + 4 <= e; i += 4) {
    a0 += b2f(h3[(size_t)(i + 0) * 64 + lane]);
    a1 += b2f(h3[(size_t)(i + 1) * 64 + lane]);
    a2 += b2f(h3[(size_t)(i + 2) * 64 + lane]);
    a3 += b2f(h3[(size_t)(i + 3) * 64 + lane]);
  }
  for (; i < e; ++i) a0 += b2f(h3[(size_t)i * 64 + lane]);
  float acc = (a0 + a1) + (a2 + a3);
  pooled[(size_t)g * 64 + lane] = acc / fmaxf((float)(e - s), 1.0f);
}

// ---------------- MFMA GEMM: [n,K]bf16 @ (Whi+Wlo) + bias (+relu) -> [n,NC]bf16 ----
// Wave owns 64 rows x NC cols (4 row-reps); block = 256 rows. W in LDS (XOR-swizzled).

template <int K, int NC, bool RELU>
__global__ __launch_bounds__(256) void gemm_mfma(const u16* __restrict__ A,
                                                 const u16* __restrict__ Wt,
                                                 const float* __restrict__ bias,
                                                 u16* __restrict__ out, int n) {
  __shared__ u16 Wl[2 * NC * K];  // <= 64 KB
  char* ldsb = (char*)Wl;
  constexpr int CH = K / 8;  // 16B chunks per row
  for (int i = threadIdx.x; i < 2 * NC * CH; i += 256) {
    int half = i / (NC * CH);
    int j = i - half * (NC * CH);
    int c = j / CH, kc = j - c * CH;
    int dstoff = half * (NC * K * 2) + c * (K * 2) + ((kc * 16) ^ ((c & 7) << 4));
    *(uint4*)(ldsb + dstoff) =
        *(const uint4*)(Wt + (size_t)half * NC * K + (size_t)c * K + kc * 8);
  }
  __syncthreads();

  const int wid = threadIdx.x >> 6;
  const int lane = threadIdx.x & 63;
  const int lr = lane & 15;
  const int lg = lane >> 4;
  const int ntiles = DIV_UP(n, 256);

  for (int t = blockIdx.x; t < ntiles; t += (int)gridDim.x) {
    const int row0 = t * 256 + wid * 64;

    f32x4 acc[4][NC / 16];
#pragma unroll
    for (int rep = 0; rep < 4; ++rep)
#pragma unroll
      for (int ct = 0; ct < NC / 16; ++ct) acc[rep][ct] = {0.f, 0.f, 0.f, 0.f};

#pragma unroll
    for (int ks = 0; ks < K / 32; ++ks) {
      bf16x8 af[4];
#pragma unroll
      for (int rep = 0; rep < 4; ++rep) {
        int ar = row0 + rep * 16 + lr;
        if (ar >= n) ar = n - 1;  // clamp; stores guarded
        af[rep] = *(const bf16x8*)(A + (size_t)ar * K + lg * 8 + ks * 32);
      }
#pragma unroll
      for (int ct = 0; ct < NC / 16; ++ct) {
        const int c = ct * 16 + lr;
        const int ko = ((ks * 64 + lg * 16) ^ ((c & 7) << 4));
        bf16x8 bh = *(const bf16x8*)(ldsb + c * (K * 2) + ko);
        bf16x8 bl = *(const bf16x8*)(ldsb + NC * K * 2 + c * (K * 2) + ko);
#pragma unroll
        for (int rep = 0; rep < 4; ++rep) {
          acc[rep][ct] = __builtin_amdgcn_mfma_f32_16x16x32_bf16(af[rep], bh, acc[rep][ct], 0, 0, 0);
          acc[rep][ct] = __builtin_amdgcn_mfma_f32_16x16x32_bf16(af[rep], bl, acc[rep][ct], 0, 0, 0);
        }
      }
    }

#pragma unroll
    for (int rep = 0; rep < 4; ++rep) {
      const int orow = row0 + rep * 16 + lg * 4;
#pragma unroll
      for (int ct = 0; ct < NC / 16; ++ct) {
        const int c = ct * 16 + lr;
        const float b = bias ? bias[c] : 0.0f;
#pragma unroll
        for (int v = 0; v < 4; ++v) {
          const int r = orow + v;
          if (r < n) {
            float o = acc[rep][ct][v] + b;
            if (RELU) o = fmaxf(o, 0.0f);
            out[(size_t)r * NC + c] = f2b(o);
          }
        }
      }
    }
  }
}

// ---------------- 5-task MLP heads ----------------

__global__ __launch_bounds__(256) void heads_kernel(const float* __restrict__ pooled,
                                                    const float* __restrict__ Wa,
                                                    const float* __restrict__ ba,
                                                    const float* __restrict__ Wb,
                                                    const float* __restrict__ bb,
                                                    float* __restrict__ outp, int G) {
  int gid = blockIdx.x * blockDim.x + threadIdx.x;
  if (gid >= 5 * G) return;
  int g = gid % G;
  int t = gid / G;
  const float* Wat = Wa + (size_t)t * 64 * 32;
  float hid[32];
#pragma unroll
  for (int j = 0; j < 32; ++j) hid[j] = ba[t * 32 + j];
  for (int d = 0; d < 64; ++d) {
    float pd = pooled[(size_t)g * 64 + d];
#pragma unroll
    for (int j = 0; j < 32; ++j) hid[j] += pd * Wat[d * 32 + j];
  }
  float o = bb[t];
#pragma unroll
  for (int j = 0; j < 32; ++j) o += fmaxf(hid[j], 0.0f) * Wb[t * 32 + j];
  outp[(size_t)t * G + g] = o;
}

// ---------------- launch ----------------

extern "C" void kernel_launch(void* const* d_in, const int* in_sizes, int n_in,
                              void* d_out, int out_size, void* d_ws, size_t ws_size,
                              hipStream_t stream) {
  (void)n_in;
  (void)ws_size;
  const float* x  = (const float*)d_in[0];
  const int* ei   = (const int*)d_in[1];
  const int* batch = (const int*)d_in[2];
  const float* W1 = (const float*)d_in[3];
  const float* b1 = (const float*)d_in[4];
  const float* W2 = (const float*)d_in[5];
  const float* b2 = (const float*)d_in[6];
  const float* W3 = (const float*)d_in[7];
  const float* b3 = (const float*)d_in[8];
  const float* Wa = (const float*)d_in[9];
  const float* ba = (const float*)d_in[10];
  const float* Wb = (const float*)d_in[11];
  const float* bb = (const float*)d_in[12];
  float* out = (float*)d_out;

  const int N = in_sizes[0] / 64;
  const int E = in_sizes[1] / 2;
  const int G = out_size / 5;
  const int* src = ei;
  const int* dst = ei + E;

  char* ws = (char*)d_ws;
  size_t off = 0;
  auto alloc = [&](size_t bytes) -> char* {
    char* p = ws + off;
    off = (off + bytes + 255) & ~(size_t)255;
    return p;
  };
  int* cnt      = (int*)alloc((size_t)N * 4);
  int* rowstart = (int*)alloc((size_t)(N + 1) * 4);
  int* cursor   = (int*)alloc((size_t)N * 4);
  int* colw     = (int*)alloc((size_t)E * 4);
  float* ew     = (float*)alloc((size_t)E * 4);
  float* dinv   = (float*)alloc((size_t)N * 4);
  const int nchunks = DIV_UP(N, 1024);  // 391 for N=400000 (<= 512)
  int* bsums    = (int*)alloc((size_t)nchunks * 4);
  int* gstart   = (int*)alloc((size_t)(G + 1) * 4);
  float* pooled = (float*)alloc((size_t)G * 64 * 4);
  u16* Wt1      = (u16*)alloc(2 * 8192 * 2);
  u16* Wt2      = (u16*)alloc(2 * 16384 * 2);
  u16* Wt3      = (u16*)alloc(2 * 8192 * 2);
  const size_t act_elems = (size_t)N * 128;
  u16* bufA     = (u16*)alloc(act_elems * 2);
  u16* bufB     = (u16*)alloc(act_elems * 2);

  hipMemsetAsync(cnt, 0, (size_t)N * 4, stream);

  count_kernel<<<DIV_UP(E, 256), 256, 0, stream>>>(dst, cnt, E);
  scan1_kernel<<<nchunks, 256, 0, stream>>>(cnt, rowstart, bsums, N);
  scan2_kernel<<<1, 512, 0, stream>>>(bsums, nchunks);
  scan3_kernel<<<DIV_UP(N, 256), 256, 0, stream>>>(rowstart, bsums, cursor, cnt, dinv, N, E);
  fill_kernel<<<DIV_UP(E, 256), 256, 0, stream>>>(src, dst, dinv, cursor, colw, ew, E);
  prep_w<<<128, 256, 0, stream>>>(W1, W2, W3, Wt1, Wt2, Wt3);
  gbounds_kernel<<<DIV_UP(G + 1, 256), 256, 0, stream>>>(batch, gstart, N, G);

  // xb (bf16 x) lives in bufA's first N*64 entries (dead before h1 is written).
  u16* xb = bufA;
  conv_x<<<DIV_UP(N * 8, 256), 256, 0, stream>>>(x, xb, N * 8);

  // t1 [N,64] in bufB; h1 [N,128] in bufA; t2 [N,128] in bufB; h2 [N,128] in bufA;
  // hw3 [N,64] in bufB; h3 [N,64] in bufA.
  agg_kernel<64, false><<<DIV_UP(N, 8), 256, 0, stream>>>(
      xb, dinv, rowstart, colw, ew, nullptr, bufB, N);
  gemm_mfma<64, 128, true><<<512, 256, 0, stream>>>(bufB, Wt1, b1, bufA, N);
  agg_kernel<128, false><<<DIV_UP(N, 8), 256, 0, stream>>>(
      bufA, dinv, rowstart, colw, ew, nullptr, bufB, N);
  gemm_mfma<128, 128, true><<<512, 256, 0, stream>>>(bufB, Wt2, b2, bufA, N);
  gemm_mfma<128, 64, false><<<512, 256, 0, stream>>>(bufA, Wt3, nullptr, bufB, N);
  agg_kernel<64, true><<<DIV_UP(N, 8), 256, 0, stream>>>(
      bufB, dinv, rowstart, colw, ew, b3, bufA, N);
  pool_kernel<<<DIV_UP(G, 4), 256, 0, stream>>>(bufA, gstart, pooled, G);
  heads_kernel<<<DIV_UP(5 * G, 256), 256, 0, stream>>>(pooled, Wa, ba, Wb, bb, out, G);
}